// Round 5
// baseline (491.841 us; speedup 1.0000x reference)
//
#include <hip/hip_runtime.h>
#include <hip/hip_fp16.h>
#include <math.h>

#define BATCH 8
#define SCAN_T 256
#define SCAN_E 8
#define SCAN_TILE (SCAN_T * SCAN_E)

// ================= ELL fast path =================
// Fused: corners histogram + ELL fill (atomic return = slot) + fp16 repack.
// Blocks [0, F/256): count+fill (critical path, launched first).
// Remaining blocks: repack vert [B][N][3] fp32 -> vh [N][B] half4 (8B).

union H2U { __half2 h; unsigned u; };

__global__ void build_kernel(const float* __restrict__ vert,
                             const int* __restrict__ faces,
                             int* __restrict__ cnt,
                             int* __restrict__ col,   // [N][C]
                             uint2* __restrict__ vh,  // [N][BATCH] half4
                             int N, int F, int C) {
    int t = blockIdx.x * blockDim.x + threadIdx.x;
    if (t < F) {
        int f = t;
        int i = faces[3 * f + 0];
        int j = faces[3 * f + 1];
        int k = faces[3 * f + 2];
        int ri = atomicAdd(&cnt[i], 2);
        int rj = atomicAdd(&cnt[j], 2);
        int rk = atomicAdd(&cnt[k], 2);
        if (ri < C - 1) *(int2*)&col[(size_t)i * C + ri] = make_int2(j, k);
        if (rj < C - 1) *(int2*)&col[(size_t)j * C + rj] = make_int2(i, k);
        if (rk < C - 1) *(int2*)&col[(size_t)k * C + rk] = make_int2(i, j);
    } else {
        int u = t - F;
        if (u < N * BATCH) {
            int v = u >> 3;
            int b = u & 7;
            size_t src = ((size_t)b * N + v) * 3;
            H2U xy, zw;
            xy.h = __floats2half2_rn(vert[src], vert[src + 1]);
            zw.h = __floats2half2_rn(vert[src + 2], 0.0f);
            uint2 w; w.x = xy.u; w.y = zw.u;
            vh[u] = w;   // u == v*8 + b
        }
    }
}

__device__ __forceinline__ void unpack_acc(uint2 r, float& ax, float& ay, float& az) {
    H2U xy, zw; xy.u = r.x; zw.u = r.y;
    float2 f0 = __half22float2(xy.h);
    float2 f1 = __half22float2(zw.h);
    ax += f0.x; ay += f0.y; az += f1.x;
}

// Thread per (v,b), b in low 3 bits. Lanes b=0..7 of one v read vh[s*8+0..7]
// = one fully-consumed 64B line per neighbor. col reads are 8-lane broadcasts.
__global__ void gather_ell_kernel(const uint2* __restrict__ vh,
                                  const int* __restrict__ cnt,
                                  const int* __restrict__ col,
                                  float* __restrict__ out, int N, int C) {
    int t = blockIdx.x * blockDim.x + threadIdx.x;
    if (t >= N * BATCH) return;
    int v = t >> 3;
    int b = t & 7;

    int c = cnt[v];
    int ce = c < C ? c : C;                   // guard vs astronomically-rare overflow
    const int* row = col + (size_t)v * C;     // 256B-aligned ELL row
    unsigned nm1 = (unsigned)(N - 1);

    float ax = 0.f, ay = 0.f, az = 0.f;
    int e = 0;
    for (; e + 4 <= ce; e += 4) {             // 4 independent gathers in flight
        int2 s01 = *(const int2*)(row + e);
        int2 s23 = *(const int2*)(row + e + 2);
        unsigned a0 = (unsigned)s01.x; a0 = a0 < nm1 ? a0 : nm1;
        unsigned a1 = (unsigned)s01.y; a1 = a1 < nm1 ? a1 : nm1;
        unsigned a2 = (unsigned)s23.x; a2 = a2 < nm1 ? a2 : nm1;
        unsigned a3 = (unsigned)s23.y; a3 = a3 < nm1 ? a3 : nm1;
        uint2 r0 = vh[((size_t)a0 << 3) + b];
        uint2 r1 = vh[((size_t)a1 << 3) + b];
        uint2 r2 = vh[((size_t)a2 << 3) + b];
        uint2 r3 = vh[((size_t)a3 << 3) + b];
        unpack_acc(r0, ax, ay, az);
        unpack_acc(r1, ax, ay, az);
        unpack_acc(r2, ax, ay, az);
        unpack_acc(r3, ax, ay, az);
    }
    for (; e + 2 <= ce; e += 2) {
        int2 ss = *(const int2*)(row + e);
        unsigned a0 = (unsigned)ss.x; a0 = a0 < nm1 ? a0 : nm1;
        unsigned a1 = (unsigned)ss.y; a1 = a1 < nm1 ? a1 : nm1;
        uint2 r0 = vh[((size_t)a0 << 3) + b];
        uint2 r1 = vh[((size_t)a1 << 3) + b];
        unpack_acc(r0, ax, ay, az);
        unpack_acc(r1, ax, ay, az);
    }

    float invd = 1.0f / fmaxf((float)c, 1.0f);
    float sx = 0.f, sy = 0.f, sz = 0.f;
    unpack_acc(vh[t], sx, sy, sz);            // self (t == v*8 + b)
    float l0 = ax * invd - sx;
    float l1 = ay * invd - sy;
    float l2 = az * invd - sz;
    out[(size_t)b * N + v] = sqrtf(l0 * l0 + l1 * l1 + l2 * l2);
}

// ================= CSR fallback (proven R4 path) =================

__global__ void count_kernel(const int* __restrict__ faces, int* __restrict__ cnt,
                             int* __restrict__ rank, int F) {
    int f = blockIdx.x * blockDim.x + threadIdx.x;
    if (f >= F) return;
    int i = faces[3 * f + 0];
    int j = faces[3 * f + 1];
    int k = faces[3 * f + 2];
    rank[3 * f + 0] = atomicAdd(&cnt[i], 2);
    rank[3 * f + 1] = atomicAdd(&cnt[j], 2);
    rank[3 * f + 2] = atomicAdd(&cnt[k], 2);
}

__global__ void scan1_kernel(const int* __restrict__ cnt, int* __restrict__ off,
                             int* __restrict__ bsums, int N) {
    __shared__ int sh[SCAN_T];
    int base = blockIdx.x * SCAN_TILE + threadIdx.x * SCAN_E;
    int vals[SCAN_E];
    int s = 0;
    #pragma unroll
    for (int e = 0; e < SCAN_E; ++e) {
        int v = (base + e < N) ? cnt[base + e] : 0;
        vals[e] = v; s += v;
    }
    sh[threadIdx.x] = s;
    __syncthreads();
    for (int d = 1; d < SCAN_T; d <<= 1) {
        int t = (threadIdx.x >= (unsigned)d) ? sh[threadIdx.x - d] : 0;
        __syncthreads();
        sh[threadIdx.x] += t;
        __syncthreads();
    }
    int excl = (threadIdx.x > 0) ? sh[threadIdx.x - 1] : 0;
    if (threadIdx.x == SCAN_T - 1) bsums[blockIdx.x] = sh[SCAN_T - 1];
    #pragma unroll
    for (int e = 0; e < SCAN_E; ++e) {
        if (base + e < N) off[base + e] = excl;
        excl += vals[e];
    }
}

__global__ void scan2_kernel(int* bsums, int nb) {
    __shared__ int sh[SCAN_T];
    if (nb <= SCAN_T) {
        int v = ((int)threadIdx.x < nb) ? bsums[threadIdx.x] : 0;
        sh[threadIdx.x] = v;
        __syncthreads();
        for (int d = 1; d < SCAN_T; d <<= 1) {
            int t = (threadIdx.x >= (unsigned)d) ? sh[threadIdx.x - d] : 0;
            __syncthreads();
            sh[threadIdx.x] += t;
            __syncthreads();
        }
        int excl = (threadIdx.x > 0) ? sh[threadIdx.x - 1] : 0;
        if ((int)threadIdx.x < nb) bsums[threadIdx.x] = excl;
    } else if (threadIdx.x == 0) {
        int run = 0;
        for (int x = 0; x < nb; ++x) { int t = bsums[x]; bsums[x] = run; run += t; }
    }
}

__global__ void scan3_kernel(int* __restrict__ off, const int* __restrict__ bsums, int N) {
    int add = bsums[blockIdx.x];
    if (add == 0) return;
    int base = blockIdx.x * SCAN_TILE + threadIdx.x * SCAN_E;
    #pragma unroll
    for (int e = 0; e < SCAN_E; ++e)
        if (base + e < N) off[base + e] += add;
}

__global__ void fill_kernel(const int* __restrict__ faces, const int* __restrict__ off,
                            const int* __restrict__ rank, int* __restrict__ col, int F) {
    int f = blockIdx.x * blockDim.x + threadIdx.x;
    if (f >= F) return;
    int i = faces[3 * f + 0];
    int j = faces[3 * f + 1];
    int k = faces[3 * f + 2];
    int ri = rank[3 * f + 0];
    int rj = rank[3 * f + 1];
    int rk = rank[3 * f + 2];
    int2* c2 = (int2*)col;
    c2[(off[i] + ri) >> 1] = make_int2(j, k);
    c2[(off[j] + rj) >> 1] = make_int2(i, k);
    c2[(off[k] + rk) >> 1] = make_int2(i, j);
}

__global__ void repack_kernel(const float* __restrict__ vert, float4* __restrict__ vs4,
                              int N) {
    int t = blockIdx.x * blockDim.x + threadIdx.x;
    if (t >= N * BATCH) return;
    int v = t >> 3;
    int b = t & 7;
    size_t src = ((size_t)b * N + v) * 3;
    vs4[t] = make_float4(vert[src], vert[src + 1], vert[src + 2], 0.0f);
}

__global__ void gather_csr_kernel(const float4* __restrict__ vs4,
                                  const int* __restrict__ cnt,
                                  const int* __restrict__ off,
                                  const int* __restrict__ col,
                                  float* __restrict__ out, int N) {
    int t = blockIdx.x * blockDim.x + threadIdx.x;
    if (t >= N * BATCH) return;
    int v = t >> 3;
    int b = t & 7;
    int c = cnt[v];
    int start = off[v];
    const int2* c2 = (const int2*)col;
    int e0 = start >> 1;
    int e1 = (start + c) >> 1;
    float ax = 0.f, ay = 0.f, az = 0.f;
    for (int e = e0; e < e1; ++e) {
        int2 ss = c2[e];
        float4 p = vs4[((size_t)ss.x << 3) + b];
        float4 q = vs4[((size_t)ss.y << 3) + b];
        ax += p.x + q.x; ay += p.y + q.y; az += p.z + q.z;
    }
    float invd = 1.0f / fmaxf((float)c, 1.0f);
    float4 self = vs4[((size_t)v << 3) + b];
    float l0 = ax * invd - self.x;
    float l1 = ay * invd - self.y;
    float l2 = az * invd - self.z;
    out[(size_t)b * N + v] = sqrtf(l0 * l0 + l1 * l1 + l2 * l2);
}

// ================= launch =================

static inline size_t align256(size_t x) { return (x + 255) & ~(size_t)255; }

extern "C" void kernel_launch(void* const* d_in, const int* in_sizes, int n_in,
                              void* d_out, int out_size, void* d_ws, size_t ws_size,
                              hipStream_t stream) {
    const float* vert  = (const float*)d_in[0];
    const int*   faces = (const int*)d_in[1];
    float*       out   = (float*)d_out;

    int N = out_size / BATCH;      // 500000
    int F = in_sizes[1] / 3;       // 1000000

    char* ws = (char*)d_ws;
    int threads = 256;

    // ---- ELL layout: cnt [N] | col [N*C] | vh [N*B] uint2 ----
    for (int C : {64, 48}) {
        size_t o_cnt = 0;
        size_t o_col = align256((size_t)N * 4);
        size_t o_vh  = o_col + align256((size_t)N * C * 4);
        size_t need  = o_vh + (size_t)N * BATCH * sizeof(uint2);
        if (ws_size >= need) {
            int*   cnt = (int*)(ws + o_cnt);
            int*   col = (int*)(ws + o_col);
            uint2* vh  = (uint2*)(ws + o_vh);

            hipMemsetAsync(cnt, 0, (size_t)N * 4, stream);

            int total_build = F + N * BATCH;
            build_kernel<<<(total_build + threads - 1) / threads, threads, 0, stream>>>(
                vert, faces, cnt, col, vh, N, F, C);

            int total = N * BATCH;
            gather_ell_kernel<<<(total + threads - 1) / threads, threads, 0, stream>>>(
                vh, cnt, col, out, N, C);
            return;
        }
    }

    // ---- CSR fallback ----
    int E = 6 * F;
    size_t o_cnt   = 0;
    size_t o_off   = align256((size_t)N * 4);
    size_t o_bsums = o_off + align256((size_t)N * 4);
    size_t o_col   = o_bsums + 4096;
    size_t o_vs4   = o_col + align256((size_t)E * 4);

    int* cnt   = (int*)(ws + o_cnt);
    int* off   = (int*)(ws + o_off);
    int* bsums = (int*)(ws + o_bsums);
    int* col   = (int*)(ws + o_col);
    float4* vs4 = (float4*)(ws + o_vs4);
    int* rank  = (int*)(ws + o_vs4);   // alias: rank dead before vs4 written

    hipMemsetAsync(cnt, 0, (size_t)N * 4, stream);

    count_kernel<<<(F + threads - 1) / threads, threads, 0, stream>>>(faces, cnt, rank, F);
    int nb = (N + SCAN_TILE - 1) / SCAN_TILE;
    scan1_kernel<<<nb, SCAN_T, 0, stream>>>(cnt, off, bsums, N);
    scan2_kernel<<<1, SCAN_T, 0, stream>>>(bsums, nb);
    scan3_kernel<<<nb, SCAN_T, 0, stream>>>(off, bsums, N);
    fill_kernel<<<(F + threads - 1) / threads, threads, 0, stream>>>(faces, off, rank, col, F);

    int total = N * BATCH;
    repack_kernel<<<(total + threads - 1) / threads, threads, 0, stream>>>(vert, vs4, N);
    gather_csr_kernel<<<(total + threads - 1) / threads, threads, 0, stream>>>(
        vs4, cnt, off, col, out, N);
}

// Round 6
// 381.687 us; speedup vs baseline: 1.2886x; 1.2886x over previous
//
#include <hip/hip_runtime.h>
#include <hip/hip_fp16.h>
#include <math.h>

#define BATCH 8
#define SCAN_T 256
#define SCAN_E 8
#define SCAN_TILE (SCAN_T * SCAN_E)   // 2048 elems per scan block

union H2U { __half2 h; unsigned u; };

// ---------------- count: PURE atomic kernel (device atomic floor ~25 G/s) ----------------
// cnt[v] += 2 per corner; rank[corner] = pre-add value (even). rank stores coalesced.
__global__ void count_kernel(const int* __restrict__ faces, int* __restrict__ cnt,
                             int* __restrict__ rank, int F) {
    int f = blockIdx.x * blockDim.x + threadIdx.x;
    if (f >= F) return;
    int i = faces[3 * f + 0];
    int j = faces[3 * f + 1];
    int k = faces[3 * f + 2];
    rank[3 * f + 0] = atomicAdd(&cnt[i], 2);
    rank[3 * f + 1] = atomicAdd(&cnt[j], 2);
    rank[3 * f + 2] = atomicAdd(&cnt[k], 2);
}

// ---------------- scan (2 kernels) ----------------
// scan_sums: per-block tile sum -> bsums[block]
__global__ void scan_sums_kernel(const int* __restrict__ cnt, int* __restrict__ bsums, int N) {
    __shared__ int sh[SCAN_T];
    int base = blockIdx.x * SCAN_TILE + threadIdx.x * SCAN_E;
    int s = 0;
    #pragma unroll
    for (int e = 0; e < SCAN_E; ++e)
        if (base + e < N) s += cnt[base + e];
    sh[threadIdx.x] = s;
    __syncthreads();
    for (int d = SCAN_T / 2; d > 0; d >>= 1) {
        if (threadIdx.x < (unsigned)d) sh[threadIdx.x] += sh[threadIdx.x + d];
        __syncthreads();
    }
    if (threadIdx.x == 0) bsums[blockIdx.x] = sh[0];
}

// scan_apply: scan bsums in LDS (nb <= SCAN_T), then block-local exclusive scan -> off
__global__ void scan_apply_kernel(const int* __restrict__ cnt, int* __restrict__ off,
                                  const int* __restrict__ bsums, int N, int nb) {
    __shared__ int shb[SCAN_T];
    __shared__ int sh[SCAN_T];
    // inclusive scan of block sums
    int bv = ((int)threadIdx.x < nb) ? bsums[threadIdx.x] : 0;
    shb[threadIdx.x] = bv;
    __syncthreads();
    for (int d = 1; d < SCAN_T; d <<= 1) {
        int t = (threadIdx.x >= (unsigned)d) ? shb[threadIdx.x - d] : 0;
        __syncthreads();
        shb[threadIdx.x] += t;
        __syncthreads();
    }
    int block_prefix = (blockIdx.x > 0) ? shb[blockIdx.x - 1] : 0;

    int base = blockIdx.x * SCAN_TILE + threadIdx.x * SCAN_E;
    int vals[SCAN_E];
    int s = 0;
    #pragma unroll
    for (int e = 0; e < SCAN_E; ++e) {
        int v = (base + e < N) ? cnt[base + e] : 0;
        vals[e] = v; s += v;
    }
    sh[threadIdx.x] = s;
    __syncthreads();
    for (int d = 1; d < SCAN_T; d <<= 1) {
        int t = (threadIdx.x >= (unsigned)d) ? sh[threadIdx.x - d] : 0;
        __syncthreads();
        sh[threadIdx.x] += t;
        __syncthreads();
    }
    int excl = block_prefix + ((threadIdx.x > 0) ? sh[threadIdx.x - 1] : 0);
    #pragma unroll
    for (int e = 0; e < SCAN_E; ++e) {
        if (base + e < N) off[base + e] = excl;
        excl += vals[e];
    }
}

// ---------------- fill + repack fused (both atomic-free, independent) ----------------
// Blocks [0, fillBlocks): CSR fill via off+rank -> aligned int2 stores.
// Remaining blocks: repack vert [B][N][3] fp32 -> vh [N][B] half4 (uint2, 8B).
__global__ void fill_repack_kernel(const int* __restrict__ faces,
                                   const int* __restrict__ off,
                                   const int* __restrict__ rank,
                                   int* __restrict__ col,
                                   const float* __restrict__ vert,
                                   uint2* __restrict__ vh,
                                   int N, int F) {
    int t = blockIdx.x * blockDim.x + threadIdx.x;
    if (t < F) {
        int f = t;
        int i = faces[3 * f + 0];
        int j = faces[3 * f + 1];
        int k = faces[3 * f + 2];
        int ri = rank[3 * f + 0];
        int rj = rank[3 * f + 1];
        int rk = rank[3 * f + 2];
        int2* c2 = (int2*)col;
        c2[(off[i] + ri) >> 1] = make_int2(j, k);
        c2[(off[j] + rj) >> 1] = make_int2(i, k);
        c2[(off[k] + rk) >> 1] = make_int2(i, j);
    } else {
        int u = t - F;
        if (u < N * BATCH) {
            int v = u >> 3;
            int b = u & 7;
            size_t src = ((size_t)b * N + v) * 3;
            H2U xy, zw;
            xy.h = __floats2half2_rn(vert[src], vert[src + 1]);
            zw.h = __floats2half2_rn(vert[src + 2], 0.0f);
            uint2 w; w.x = xy.u; w.y = zw.u;
            vh[u] = w;   // u == v*8 + b
        }
    }
}

__device__ __forceinline__ void unpack_acc(uint2 r, float& ax, float& ay, float& az) {
    H2U xy, zw; xy.u = r.x; zw.u = r.y;
    float2 f0 = __half22float2(xy.h);
    float2 f1 = __half22float2(zw.h);
    ax += f0.x; ay += f0.y; az += f1.x;
}

// ---------------- gather + finalize: thread per (v,b), b in low 3 bits ----------------
// Lanes b=0..7 of one v read vh[s*8 + 0..7] = one fully-consumed 64B line per neighbor.
// col reads: packed CSR, int2 (2 edges), broadcast across the 8 b-lanes.
__global__ void gather_kernel(const uint2* __restrict__ vh,
                              const int* __restrict__ cnt,
                              const int* __restrict__ off,
                              const int* __restrict__ col,
                              float* __restrict__ out, int N) {
    int t = blockIdx.x * blockDim.x + threadIdx.x;
    if (t >= N * BATCH) return;
    int v = t >> 3;
    int b = t & 7;

    int c = cnt[v];
    int start = off[v];              // even
    const int2* c2 = (const int2*)col;
    int e0 = start >> 1;
    int e1 = (start + c) >> 1;

    float ax = 0.f, ay = 0.f, az = 0.f;
    int e = e0;
    for (; e + 2 <= e1; e += 2) {    // 4 independent vh gathers in flight
        int2 s01 = c2[e];
        int2 s23 = c2[e + 1];
        uint2 r0 = vh[((size_t)s01.x << 3) + b];
        uint2 r1 = vh[((size_t)s01.y << 3) + b];
        uint2 r2 = vh[((size_t)s23.x << 3) + b];
        uint2 r3 = vh[((size_t)s23.y << 3) + b];
        unpack_acc(r0, ax, ay, az);
        unpack_acc(r1, ax, ay, az);
        unpack_acc(r2, ax, ay, az);
        unpack_acc(r3, ax, ay, az);
    }
    for (; e < e1; ++e) {
        int2 ss = c2[e];
        uint2 r0 = vh[((size_t)ss.x << 3) + b];
        uint2 r1 = vh[((size_t)ss.y << 3) + b];
        unpack_acc(r0, ax, ay, az);
        unpack_acc(r1, ax, ay, az);
    }

    float invd = 1.0f / fmaxf((float)c, 1.0f);
    float sx = 0.f, sy = 0.f, sz = 0.f;
    unpack_acc(vh[t], sx, sy, sz);   // self (t == v*8 + b)
    float l0 = ax * invd - sx;
    float l1 = ay * invd - sy;
    float l2 = az * invd - sz;
    out[(size_t)b * N + v] = sqrtf(l0 * l0 + l1 * l1 + l2 * l2);
}

// ---------------- fp32 scalar fallback (tiny ws) ----------------

__global__ void gather_scalar_kernel(const float* __restrict__ vert,
                                     const int* __restrict__ cnt,
                                     const int* __restrict__ off,
                                     const int* __restrict__ col,
                                     float* __restrict__ out, int N) {
    int v = blockIdx.x * blockDim.x + threadIdx.x;
    if (v >= N) return;
    int c = cnt[v];
    int start = off[v];
    int end = start + c;
    float ax[BATCH], ay[BATCH], az[BATCH];
    #pragma unroll
    for (int b = 0; b < BATCH; ++b) { ax[b] = 0.f; ay[b] = 0.f; az[b] = 0.f; }
    for (int e = start; e < end; ++e) {
        int s = col[e];
        #pragma unroll
        for (int b = 0; b < BATCH; ++b) {
            size_t base = ((size_t)b * N + s) * 3;
            ax[b] += vert[base + 0];
            ay[b] += vert[base + 1];
            az[b] += vert[base + 2];
        }
    }
    float invd = 1.0f / fmaxf((float)c, 1.0f);
    #pragma unroll
    for (int b = 0; b < BATCH; ++b) {
        size_t base = ((size_t)b * N + v) * 3;
        float l0 = ax[b] * invd - vert[base + 0];
        float l1 = ay[b] * invd - vert[base + 1];
        float l2 = az[b] * invd - vert[base + 2];
        out[(size_t)b * N + v] = sqrtf(l0 * l0 + l1 * l1 + l2 * l2);
    }
}

__global__ void fill_only_kernel(const int* __restrict__ faces, const int* __restrict__ off,
                                 const int* __restrict__ rank, int* __restrict__ col, int F) {
    int f = blockIdx.x * blockDim.x + threadIdx.x;
    if (f >= F) return;
    int i = faces[3 * f + 0];
    int j = faces[3 * f + 1];
    int k = faces[3 * f + 2];
    int2* c2 = (int2*)col;
    c2[(off[i] + rank[3 * f + 0]) >> 1] = make_int2(j, k);
    c2[(off[j] + rank[3 * f + 1]) >> 1] = make_int2(i, k);
    c2[(off[k] + rank[3 * f + 2]) >> 1] = make_int2(i, j);
}

// ---------------- launch ----------------

static inline size_t align256(size_t x) { return (x + 255) & ~(size_t)255; }

extern "C" void kernel_launch(void* const* d_in, const int* in_sizes, int n_in,
                              void* d_out, int out_size, void* d_ws, size_t ws_size,
                              hipStream_t stream) {
    const float* vert  = (const float*)d_in[0];
    const int*   faces = (const int*)d_in[1];
    float*       out   = (float*)d_out;

    int N = out_size / BATCH;      // 500000
    int F = in_sizes[1] / 3;       // 1000000
    int E = 6 * F;

    char* ws = (char*)d_ws;
    int threads = 256;
    int nb = (N + SCAN_TILE - 1) / SCAN_TILE;   // 245 for N=500000

    // Layout: cnt[N] | off[N] | bsums[1024] | col[E] | vh[N*B]uint2 | rank[3F]
    size_t o_cnt   = 0;
    size_t o_off   = align256((size_t)N * 4);
    size_t o_bsums = o_off + align256((size_t)N * 4);
    size_t o_col   = o_bsums + 4096;
    size_t o_vh    = o_col + align256((size_t)E * 4);
    size_t o_rank  = o_vh + align256((size_t)N * BATCH * sizeof(uint2));
    size_t need    = o_rank + (size_t)3 * F * 4;

    int* cnt   = (int*)(ws + o_cnt);
    int* off   = (int*)(ws + o_off);
    int* bsums = (int*)(ws + o_bsums);
    int* col   = (int*)(ws + o_col);

    hipMemsetAsync(cnt, 0, (size_t)N * 4, stream);

    if (ws_size >= need && nb <= SCAN_T) {
        uint2* vh  = (uint2*)(ws + o_vh);
        int*   rank = (int*)(ws + o_rank);

        count_kernel<<<(F + threads - 1) / threads, threads, 0, stream>>>(faces, cnt, rank, F);
        scan_sums_kernel<<<nb, SCAN_T, 0, stream>>>(cnt, bsums, N);
        scan_apply_kernel<<<nb, SCAN_T, 0, stream>>>(cnt, off, bsums, N, nb);

        int total_fr = F + N * BATCH;
        fill_repack_kernel<<<(total_fr + threads - 1) / threads, threads, 0, stream>>>(
            faces, off, rank, col, vert, vh, N, F);

        int total = N * BATCH;
        gather_kernel<<<(total + threads - 1) / threads, threads, 0, stream>>>(
            vh, cnt, off, col, out, N);
        return;
    }

    // ---- compact fp32 fallback (rank aliases region after col) ----
    size_t o_rank2 = o_vh;
    int* rank = (int*)(ws + o_rank2);

    count_kernel<<<(F + threads - 1) / threads, threads, 0, stream>>>(faces, cnt, rank, F);
    scan_sums_kernel<<<nb, SCAN_T, 0, stream>>>(cnt, bsums, N);
    scan_apply_kernel<<<nb, SCAN_T, 0, stream>>>(cnt, off, bsums, N, nb);
    fill_only_kernel<<<(F + threads - 1) / threads, threads, 0, stream>>>(faces, off, rank, col, F);
    gather_scalar_kernel<<<(N + threads - 1) / threads, threads, 0, stream>>>(
        vert, cnt, off, col, out, N);
}